// Round 3
// baseline (153.232 us; speedup 1.0000x reference)
//
#include <hip/hip_runtime.h>
#include <math.h>

// Problem constants (from reference): N=256, B=8, S=14, PILOTS=[0,7], U=1
static constexpr int kN   = 256;
static constexpr int kB   = 8;
static constexpr int kS   = 14;
static constexpr int kNSH = 12;   // S - len(PILOTS)
static constexpr int kBS  = kB * kS;  // 112

// ---------------------------------------------------------------------------
// Kernel 1: per (b,s) block computes h[k] = DFT(x[b,s,:])[k] * conj(zc[k])
// Derivation: h_freq_est (pre-einsum) == fft(x, axis=-1) * conj(zc):
//   fft(ifft_ortho(zc)) = sqrt(N)*zc; the sqrt(N) cancels the /sqrt(N);
//   fft(ifft(Y)) == Y with default numpy norms.
// ---------------------------------------------------------------------------
__global__ __launch_bounds__(256) void dft_zc_kernel(
    const float* __restrict__ xr, const float* __restrict__ xi,
    const float* __restrict__ zcr, const float* __restrict__ zci,
    float* __restrict__ hre, float* __restrict__ him)
{
    __shared__ float sxr[kN];
    __shared__ float sxi[kN];
    const int bs = blockIdx.x;        // 0..111  (b*S + s)
    const int k  = threadIdx.x;       // 0..255  (output frequency bin)

    sxr[k] = xr[bs * kN + k];
    sxi[k] = xi[bs * kN + k];

    const float two_pi_over_N = 6.283185307179586476925f / (float)kN;
    float wi, wr;
    sincosf(-two_pi_over_N * (float)k, &wi, &wr);   // w = e^{-2*pi*i*k/N}

    __syncthreads();

    float Hr = 0.0f, Hi = 0.0f;

    for (int n0 = 0; n0 < kN; n0 += 32) {
        // exact integer phase reduction: cur = e^{-2*pi*i*((k*n0) mod N)/N}
        const int p = (k * n0) & (kN - 1);
        float ci, cr;
        sincosf(-two_pi_over_N * (float)p, &ci, &cr);
        #pragma unroll
        for (int j = 0; j < 32; ++j) {
            const int n = n0 + j;
            const float a = sxr[n];   // wave-uniform broadcast (free)
            const float b = sxi[n];
            Hr = fmaf(a, cr, fmaf(-b, ci, Hr));
            Hi = fmaf(a, ci, fmaf( b, cr, Hi));
            const float nr = cr * wr - ci * wi;
            const float ni = cr * wi + ci * wr;
            cr = nr; ci = ni;
        }
    }

    // h = H * conj(zc)
    const float zr = zcr[k], zi = zci[k];
    hre[bs * kN + k] = fmaf(Hr, zr,  Hi * zi);
    him[bs * kN + k] = fmaf(Hi, zr, -Hr * zi);
}

// ---------------------------------------------------------------------------
// Kernel 2: out[b,s,n] = sum_m cov[c(b,s), n, m] * h[b,s,m]   (complex)
// Output layout: PLANAR — real plane (B*S*N floats) then imag plane.
// Grid: 4 blocks per (b,s); each block 256 threads = 4 waves; each wave does
// 16 rows n. For one row the 64 lanes float4-load the full contiguous 1 KB
// cov row (perfectly coalesced), FMA against the lane's fixed h fragment held
// in registers, then 64-lane butterfly reduce.
// ---------------------------------------------------------------------------
__global__ __launch_bounds__(256) void matvec_kernel(
    const float* __restrict__ covr, const float* __restrict__ covi,
    const float* __restrict__ hre, const float* __restrict__ him,
    const int*  __restrict__ shift, const int* __restrict__ gidx,
    float* __restrict__ out)
{
    const int bs = blockIdx.x >> 2;     // (b*S + s), 0..111
    const int q  = blockIdx.x & 3;      // row quarter 0..3
    const int s  = bs % kS;
    const int b  = bs / kS;

    // complete[b,s]: padded-zero column 0 gathered; gidx==0 -> index 0,
    // else shift_val[b, gidx-1]
    const int g = gidx[s];
    const int c = (g == 0) ? 0 : shift[b * kNSH + (g - 1)];

    const int tid = threadIdx.x;
    const int w   = tid >> 6;           // wave 0..3
    const int l   = tid & 63;           // lane

    // Lane's fixed h fragment: m = l*4 + j  (coalesced float4 loads)
    const float4 hr = ((const float4*)(hre + bs * kN))[l];
    const float4 hi = ((const float4*)(him + bs * kN))[l];

    const long base = (long)c * (long)(kN * kN);
    const int n0 = q * 64 + w * 16;

    for (int r = 0; r < 16; ++r) {
        const int n = n0 + r;
        const float4 mr = ((const float4*)(covr + base + (long)n * kN))[l];
        const float4 mi = ((const float4*)(covi + base + (long)n * kN))[l];

        float ar = mr.x*hr.x + mr.y*hr.y + mr.z*hr.z + mr.w*hr.w
                 - (mi.x*hi.x + mi.y*hi.y + mi.z*hi.z + mi.w*hi.w);
        float ai = mr.x*hi.x + mr.y*hi.y + mr.z*hi.z + mr.w*hi.w
                 +  mi.x*hr.x + mi.y*hr.y + mi.z*hr.z + mi.w*hr.w;

        #pragma unroll
        for (int off = 32; off > 0; off >>= 1) {
            ar += __shfl_xor(ar, off, 64);
            ai += __shfl_xor(ai, off, 64);
        }
        if (l == 0) {
            // PLANAR complex layout: [Re plane | Im plane]
            out[(long)bs * kN + n]                  = ar;
            out[(long)(kBS * kN) + (long)bs * kN + n] = ai;
        }
    }
}

extern "C" void kernel_launch(void* const* d_in, const int* in_sizes, int n_in,
                              void* d_out, int out_size, void* d_ws, size_t ws_size,
                              hipStream_t stream) {
    const float* xr    = (const float*)d_in[0];  // (B,S,N)
    const float* xi    = (const float*)d_in[1];  // (B,S,N)
    const float* covr  = (const float*)d_in[2];  // (N,N,N)
    const float* covi  = (const float*)d_in[3];  // (N,N,N)
    const float* zcr   = (const float*)d_in[4];  // (N,)
    const float* zci   = (const float*)d_in[5];  // (N,)
    const int*   shift = (const int*)d_in[6];    // (B, S-2)
    const int*   gidx  = (const int*)d_in[7];    // (S,)

    float* hre = (float*)d_ws;                   // 112*256 floats
    float* him = hre + kBS * kN;                 // 112*256 floats

    dft_zc_kernel<<<kBS, 256, 0, stream>>>(xr, xi, zcr, zci, hre, him);
    matvec_kernel<<<kBS * 4, 256, 0, stream>>>(covr, covi, hre, him, shift, gidx,
                                               (float*)d_out);
}

// Round 4
// 148.108 us; speedup vs baseline: 1.0346x; 1.0346x over previous
//
#include <hip/hip_runtime.h>
#include <math.h>

// Problem constants (from reference): N=256, B=8, S=14, PILOTS=[0,7], U=1
static constexpr int kN   = 256;
static constexpr int kB   = 8;
static constexpr int kS   = 14;
static constexpr int kNSH = 12;   // S - len(PILOTS)
static constexpr int kBS  = kB * kS;  // 112

// ---------------------------------------------------------------------------
// Kernel 1: per (b,s) block computes h[k] = DFT(x[b,s,:])[k] * conj(zc[k])
// Derivation: h_freq_est (pre-einsum) == fft(x, axis=-1) * conj(zc):
//   fft(ifft_ortho(zc)) = sqrt(N)*zc; the sqrt(N) cancels the /sqrt(N);
//   fft(ifft(Y)) == Y with default numpy norms.
// ---------------------------------------------------------------------------
__global__ __launch_bounds__(256) void dft_zc_kernel(
    const float* __restrict__ xr, const float* __restrict__ xi,
    const float* __restrict__ zcr, const float* __restrict__ zci,
    float* __restrict__ hre, float* __restrict__ him)
{
    __shared__ float sxr[kN];
    __shared__ float sxi[kN];
    const int bs = blockIdx.x;        // 0..111  (b*S + s)
    const int k  = threadIdx.x;       // 0..255  (output frequency bin)

    sxr[k] = xr[bs * kN + k];
    sxi[k] = xi[bs * kN + k];

    const float two_pi_over_N = 6.283185307179586476925f / (float)kN;
    float wi, wr;
    sincosf(-two_pi_over_N * (float)k, &wi, &wr);   // w = e^{-2*pi*i*k/N}

    __syncthreads();

    float Hr = 0.0f, Hi = 0.0f;

    for (int n0 = 0; n0 < kN; n0 += 32) {
        // exact integer phase reduction: cur = e^{-2*pi*i*((k*n0) mod N)/N}
        const int p = (k * n0) & (kN - 1);
        float ci, cr;
        sincosf(-two_pi_over_N * (float)p, &ci, &cr);
        #pragma unroll
        for (int j = 0; j < 32; ++j) {
            const int n = n0 + j;
            const float a = sxr[n];   // wave-uniform broadcast (free)
            const float b = sxi[n];
            Hr = fmaf(a, cr, fmaf(-b, ci, Hr));
            Hi = fmaf(a, ci, fmaf( b, cr, Hi));
            const float nr = cr * wr - ci * wi;
            const float ni = cr * wi + ci * wr;
            cr = nr; ci = ni;
        }
    }

    // h = H * conj(zc)
    const float zr = zcr[k], zi = zci[k];
    hre[bs * kN + k] = fmaf(Hr, zr,  Hi * zi);
    him[bs * kN + k] = fmaf(Hi, zr, -Hr * zi);
}

// ---------------------------------------------------------------------------
// Kernel 2: out[b,s,n] = sum_m cov[c(b,s), n, m] * h[b,s,m]   (complex)
// Output layout: PLANAR — real plane (B*S*N floats) then imag plane.
// Grid: 8 blocks per (b,s), 256 thr = 4 waves; each wave owns 8 rows as a
// BATCH: all 16 float4 cov loads issued up-front (16 KB in flight per wave
// for memory-level parallelism), then 8 independent complex dot partials,
// then the 6-level 64-lane butterfly interleaved across the 8 rows so the
// shuffle chains pipeline instead of serializing.
// ---------------------------------------------------------------------------
__global__ __launch_bounds__(256) void matvec_kernel(
    const float* __restrict__ covr, const float* __restrict__ covi,
    const float* __restrict__ hre, const float* __restrict__ him,
    const int*  __restrict__ shift, const int* __restrict__ gidx,
    float* __restrict__ out)
{
    const int bs = blockIdx.x >> 3;     // (b*S + s), 0..111
    const int o  = blockIdx.x & 7;      // row octant 0..7
    const int s  = bs % kS;
    const int b  = bs / kS;

    // complete[b,s]: padded-zero column 0 gathered; gidx==0 -> index 0,
    // else shift_val[b, gidx-1]
    const int g = gidx[s];
    const int c = (g == 0) ? 0 : shift[b * kNSH + (g - 1)];

    const int tid = threadIdx.x;
    const int w   = tid >> 6;           // wave 0..3
    const int l   = tid & 63;           // lane

    // Lane's fixed h fragment: m = l*4 + j  (coalesced float4 loads)
    const float4 hr = ((const float4*)(hre + bs * kN))[l];
    const float4 hi = ((const float4*)(him + bs * kN))[l];

    const long base = (long)c * (long)(kN * kN);
    const float* __restrict__ rb = covr + base;
    const float* __restrict__ ib = covi + base;
    const int n0 = o * 32 + w * 8;      // this wave's first row

    // Issue all 16 loads before any compute (MLP)
    float4 mr[8], mi[8];
    #pragma unroll
    for (int r = 0; r < 8; ++r) {
        mr[r] = ((const float4*)(rb + (long)(n0 + r) * kN))[l];
        mi[r] = ((const float4*)(ib + (long)(n0 + r) * kN))[l];
    }

    float ar[8], ai[8];
    #pragma unroll
    for (int r = 0; r < 8; ++r) {
        ar[r] = mr[r].x*hr.x + mr[r].y*hr.y + mr[r].z*hr.z + mr[r].w*hr.w
              - (mi[r].x*hi.x + mi[r].y*hi.y + mi[r].z*hi.z + mi[r].w*hi.w);
        ai[r] = mr[r].x*hi.x + mr[r].y*hi.y + mr[r].z*hi.z + mr[r].w*hi.w
              +  mi[r].x*hr.x + mi[r].y*hr.y + mi[r].z*hr.z + mi[r].w*hr.w;
    }

    // Butterfly reduce: outer loop = level, inner loop = 8 independent rows
    // (16 independent shuffle chains in flight per level)
    #pragma unroll
    for (int off = 32; off > 0; off >>= 1) {
        #pragma unroll
        for (int r = 0; r < 8; ++r) {
            ar[r] += __shfl_xor(ar[r], off, 64);
            ai[r] += __shfl_xor(ai[r], off, 64);
        }
    }

    if (l == 0) {
        #pragma unroll
        for (int r = 0; r < 8; ++r) {
            // PLANAR complex layout: [Re plane | Im plane]
            out[(long)bs * kN + n0 + r]                    = ar[r];
            out[(long)(kBS * kN) + (long)bs * kN + n0 + r] = ai[r];
        }
    }
}

extern "C" void kernel_launch(void* const* d_in, const int* in_sizes, int n_in,
                              void* d_out, int out_size, void* d_ws, size_t ws_size,
                              hipStream_t stream) {
    const float* xr    = (const float*)d_in[0];  // (B,S,N)
    const float* xi    = (const float*)d_in[1];  // (B,S,N)
    const float* covr  = (const float*)d_in[2];  // (N,N,N)
    const float* covi  = (const float*)d_in[3];  // (N,N,N)
    const float* zcr   = (const float*)d_in[4];  // (N,)
    const float* zci   = (const float*)d_in[5];  // (N,)
    const int*   shift = (const int*)d_in[6];    // (B, S-2)
    const int*   gidx  = (const int*)d_in[7];    // (S,)

    float* hre = (float*)d_ws;                   // 112*256 floats
    float* him = hre + kBS * kN;                 // 112*256 floats

    dft_zc_kernel<<<kBS, 256, 0, stream>>>(xr, xi, zcr, zci, hre, him);
    matvec_kernel<<<kBS * 8, 256, 0, stream>>>(covr, covi, hre, him, shift, gidx,
                                               (float*)d_out);
}